// Round 21
// baseline (175.652 us; speedup 1.0000x reference)
//
#include <hip/hip_runtime.h>
#include <hip/hip_bf16.h>

typedef __attribute__((ext_vector_type(4))) float f32x4;
typedef __attribute__((ext_vector_type(8))) short short8;
typedef unsigned short u16;

#define NROWS 8192
#define DM 1024
#define EPSF 1e-8f
#define NRB 64        // 128-row blocks
#define NRB2 32       // 256-row blocks
#define NOFF2 496     // NRB2*(NRB2-1)/2 strict-upper 256-tiles
#define NMIX 32       // mixed 128-tiles (2i, 2i+1)
#define NSLOT 33      // slot 0 diag+mixed(merged), 1 mixed(pre-merge), 2..32 off256
#define RCAP 32       // per-row cap for 128-tile gate (lambda ~9)
#define OCAP 256
#define RCAP2 24      // per-row cap for 256-tile gate (lambda ~6)
#define OCAP2 512

#define GLDS(gsrc, ldst) __builtin_amdgcn_global_load_lds(                 \
    (const __attribute__((address_space(1))) void*)(gsrc),                 \
    (__attribute__((address_space(3))) void*)(ldst), 16, 0, 0)

static __device__ __forceinline__ u16 f2bf(float x) {
  unsigned u = __float_as_uint(x);
  u += 0x7fffu + ((u >> 16) & 1u);   // RNE
  return (u16)(u >> 16);
}

static __device__ __forceinline__ void topk9_insert(float (&S)[9], float v) {
  if (v <= S[8]) return;
  S[8] = v;
#pragma unroll
  for (int q = 8; q > 0; --q) {
    float a = S[q - 1], b = S[q];
    S[q - 1] = fmaxf(a, b);
    S[q]     = fminf(a, b);
  }
}

// vectorized scan of a 32-col strip of one spilled row (rotate-slot layout)
static __device__ __forceinline__ void scan_row_strip8(
    float (&S)[9], const float* __restrict__ crow, int row, int cbase) {
#pragma unroll
  for (int g = 0; g < 8; ++g) {
    const int c0   = cbase + 4 * g;
    const int slot = ((c0 >> 2) + row) & 31;
    const f32x4 v  = *(const f32x4*)(crow + (slot << 2));
    const float m  = fmaxf(fmaxf(v.x, v.y), fmaxf(v.z, v.w));
    if (m > S[8]) {
      topk9_insert(S, v.x); topk9_insert(S, v.y);
      topk9_insert(S, v.z); topk9_insert(S, v.w);
    }
  }
}

// ================= 128-tile building blocks (proven, R17) =================
static __device__ __forceinline__ void stage_tile8(
    const char* __restrict__ Abase, const char* __restrict__ Bbase,
    int k0b, char* smem, int aoff, int boff, int t)
{
  const int wbase = t & ~63;
#pragma unroll
  for (int it = 0; it < 2; ++it) {
    const int p  = it * 512 + t;
    const int so = (p >> 3) * (DM * 2) + (((p & 7) ^ ((p >> 3) & 7)) * 16);
    GLDS(Abase + k0b + so, smem + aoff + (it * 512 + wbase) * 16);
    GLDS(Bbase + k0b + so, smem + boff + (it * 512 + wbase) * 16);
  }
}

static __device__ __forceinline__ void stage_tileA(
    const char* __restrict__ Abase, int k0b, char* smem, int aoff, int t)
{
  const int wbase = t & ~63;
#pragma unroll
  for (int it = 0; it < 2; ++it) {
    const int p  = it * 512 + t;
    const int so = (p >> 3) * (DM * 2) + (((p & 7) ^ ((p >> 3) & 7)) * 16);
    GLDS(Abase + k0b + so, smem + aoff + (it * 512 + wbase) * 16);
  }
}

static __device__ __forceinline__ void compute_tile8(
    f32x4 (&acc)[4][2], const u16* __restrict__ As, const u16* __restrict__ Bs,
    int lane, int wr, int wc)
{
#pragma unroll
  for (int ks = 0; ks < 2; ++ks) {
    const int co = ((ks * 4 + (lane >> 4)) ^ (lane & 7)) * 8;
    short8 b[2];
#pragma unroll
    for (int j = 0; j < 2; ++j)
      b[j] = *(const short8*)(Bs + (wc + j * 16 + (lane & 15)) * 64 + co);
#pragma unroll
    for (int i = 0; i < 4; ++i) {
      const short8 a = *(const short8*)(As + (wr + i * 16 + (lane & 15)) * 64 + co);
#pragma unroll
      for (int j = 0; j < 2; ++j)
        acc[i][j] = __builtin_amdgcn_mfma_f32_16x16x32_bf16(a, b[j], acc[i][j], 0, 0, 0);
    }
  }
}

static __device__ __forceinline__ void gemm_tile8(
    f32x4 (&acc)[4][2], const char* Abase, const char* Bbase,
    char* smem, int t, int lane, int wr, int wc)
{
  u16* A0s = (u16*)smem;
  u16* B0s = (u16*)(smem + 16384);
  u16* A1s = (u16*)(smem + 32768);
  u16* B1s = (u16*)(smem + 49152);
  stage_tile8(Abase, Bbase, 0, smem, 0, 16384, t);
  __syncthreads();
  for (int kkp = 0; kkp < 8; ++kkp) {
    const int kb = kkp * 256;
    stage_tile8(Abase, Bbase, kb + 128, smem, 32768, 49152, t);
    compute_tile8(acc, A0s, B0s, lane, wr, wc);
    __syncthreads();
    if (kkp < 7)
      stage_tile8(Abase, Bbase, kb + 256, smem, 0, 16384, t);
    compute_tile8(acc, A1s, B1s, lane, wr, wc);
    __syncthreads();
  }
}

static __device__ __forceinline__ void gemm_tile8_diag(
    f32x4 (&acc)[4][2], const char* Abase,
    char* smem, int t, int lane, int wr, int wc)
{
  u16* A0s = (u16*)smem;
  u16* A1s = (u16*)(smem + 16384);
  stage_tileA(Abase, 0, smem, 0, t);
  __syncthreads();
  for (int kkp = 0; kkp < 8; ++kkp) {
    const int kb = kkp * 256;
    stage_tileA(Abase, kb + 128, smem, 16384, t);
    compute_tile8(acc, A0s, A0s, lane, wr, wc);
    __syncthreads();
    if (kkp < 7)
      stage_tileA(Abase, kb + 256, smem, 0, t);
    compute_tile8(acc, A1s, A1s, lane, wr, wc);
    __syncthreads();
  }
}

static __device__ __forceinline__ void spill_normal8(
    float* Cs, const f32x4 (&acc)[4][2], int lane, int wr, int wc)
{
#pragma unroll
  for (int i = 0; i < 4; ++i)
#pragma unroll
    for (int j = 0; j < 2; ++j)
#pragma unroll
      for (int q = 0; q < 4; ++q) {
        const int rr = wr + i * 16 + (lane >> 4) * 4 + q;
        const int cc = wc + j * 16 + (lane & 15);
        const int slot = ((cc >> 2) + rr) & 31;
        Cs[rr * 128 + (slot << 2) + (cc & 3)] = acc[i][j][q];
      }
}

// ================= 256-tile counted-vmcnt ring (BK=32, 4 x 32 KB) =================
// buffer: A [256 rows][4 chunks of 16B] at +0, B same at +16384. Logical chunk
// l stored at phys slot s = l ^ ((row>>4-ish)) via l = (p&3) ^ ((p>>4)&3);
// read slot = (lane>>4) ^ ((lane>>2)&3) -> 2 lanes/bank (free).
static __device__ __forceinline__ void stage256r(
    const char* __restrict__ A, const char* __restrict__ B,
    int k0b, char* smem, int buf, int t)
{
  const int wbase = t & ~63;
#pragma unroll
  for (int it = 0; it < 2; ++it) {
    const int p   = it * 512 + t;          // chunk 0..1023
    const int row = p >> 2;
    const int l   = (p & 3) ^ ((p >> 4) & 3);
    const size_t go = (size_t)row * (DM * 2) + k0b + l * 16;
    GLDS(A + go, smem + buf * 32768 + (it * 512 + wbase) * 16);
    GLDS(B + go, smem + buf * 32768 + 16384 + (it * 512 + wbase) * 16);
  }
}

// one BK=32 K-step: wave tile 128x64, acc[8][4]; row stride 32 u16 (64 B)
static __device__ __forceinline__ void compute256r(
    f32x4 (&acc)[8][4], const u16* __restrict__ Ls, int lane, int wm, int wn)
{
  const u16* As = Ls;
  const u16* Bs = Ls + 8192;               // +16384 bytes
  const int co = ((lane >> 4) ^ ((lane >> 2) & 3)) * 8;
  short8 b[4];
#pragma unroll
  for (int j = 0; j < 4; ++j)
    b[j] = *(const short8*)(Bs + (wn * 64 + j * 16 + (lane & 15)) * 32 + co);
#pragma unroll
  for (int i = 0; i < 8; ++i) {
    const short8 a = *(const short8*)(As + (wm * 128 + i * 16 + (lane & 15)) * 32 + co);
#pragma unroll
    for (int j = 0; j < 4; ++j)
      acc[i][j] = __builtin_amdgcn_mfma_f32_16x16x32_bf16(a, b[j], acc[i][j], 0, 0, 0);
  }
}

// ---------------- kernel 1: row norm -> bf16 F, content logits ----------------
__global__ __launch_bounds__(256) void k_rowprep(
    const float* __restrict__ H, const float* __restrict__ Wc,
    const float* __restrict__ bc, u16* __restrict__ F, float* __restrict__ CL)
{
  const int r = blockIdx.x;
  const int t = threadIdx.x;
  const int lane = t & 63;
  const int w = t >> 6;

  const float4 h  = ((const float4*)(H  + (size_t)r * DM))[t];
  const float4 c0 = ((const float4*)(Wc + 0 * DM))[t];
  const float4 c1 = ((const float4*)(Wc + 1 * DM))[t];
  const float4 c2 = ((const float4*)(Wc + 2 * DM))[t];

  float ss = h.x*h.x + h.y*h.y + h.z*h.z + h.w*h.w;
  float d0 = h.x*c0.x + h.y*c0.y + h.z*c0.z + h.w*c0.w;
  float d1 = h.x*c1.x + h.y*c1.y + h.z*c1.z + h.w*c1.w;
  float d2 = h.x*c2.x + h.y*c2.y + h.z*c2.z + h.w*c2.w;

#pragma unroll
  for (int off = 32; off > 0; off >>= 1) {
    ss += __shfl_down(ss, off);
    d0 += __shfl_down(d0, off);
    d1 += __shfl_down(d1, off);
    d2 += __shfl_down(d2, off);
  }
  __shared__ float red[4][4];
  __shared__ float bcast;
  if (lane == 0) { red[w][0] = ss; red[w][1] = d0; red[w][2] = d1; red[w][3] = d2; }
  __syncthreads();
  if (t == 0) {
    float S  = red[0][0] + red[1][0] + red[2][0] + red[3][0];
    float D0 = red[0][1] + red[1][1] + red[2][1] + red[3][1];
    float D1 = red[0][2] + red[1][2] + red[2][2] + red[3][2];
    float D2 = red[0][3] + red[1][3] + red[2][3] + red[3][3];
    bcast = 1.0f / (sqrtf(S) + EPSF);
    CL[r*3+0] = D0 + bc[0];
    CL[r*3+1] = D1 + bc[1];
    CL[r*3+2] = D2 + bc[2];
  }
  __syncthreads();
  const float invn = bcast;
  ushort4 o;
  o.x = f2bf(h.x * invn); o.y = f2bf(h.y * invn);
  o.z = f2bf(h.z * invn); o.w = f2bf(h.w * invn);
  ((ushort4*)(F + (size_t)r * DM))[t] = o;
}

// ---------------- kernel 2a: 128-diag tiles -> slot 0 + bound9d ----------------
__global__ __launch_bounds__(512) void k_diag(
    const u16* __restrict__ F, float* __restrict__ partials, float* __restrict__ bound9d)
{
  const int rb = blockIdx.x;
  __shared__ char smem[65536];
  float* Cs = (float*)smem;
  float* Ms = (float*)smem;

  const int t    = threadIdx.x;
  const int lane = t & 63;
  const int w    = t >> 6;
  const int wr   = (w >> 2) * 64;
  const int wc   = (w & 3) * 32;
  const int R0   = rb * 128;

  f32x4 acc[4][2];
#pragma unroll
  for (int i = 0; i < 4; ++i)
#pragma unroll
    for (int j = 0; j < 2; ++j)
      acc[i][j] = {0.f, 0.f, 0.f, 0.f};

  gemm_tile8_diag(acc, (const char*)(F + (size_t)R0 * DM), smem, t, lane, wr, wc);

  spill_normal8(Cs, acc, lane, wr, wc);
  __syncthreads();

  float sR[9];
#pragma unroll
  for (int q = 0; q < 9; ++q) sR[q] = -1e30f;
  scan_row_strip8(sR, Cs + (t >> 2) * 128, t >> 2, (t & 3) * 32);
  __syncthreads();

#pragma unroll
  for (int q = 0; q < 9; ++q) Ms[(t >> 2) * 36 + (t & 3) * 9 + q] = sR[q];
  __syncthreads();
  if (t < 128) {
    const float* row = Ms + t * 36;
    float T[9];
#pragma unroll
    for (int q = 0; q < 9; ++q) T[q] = row[q];
#pragma unroll
    for (int grp = 1; grp < 4; ++grp) {
      for (int gq = 0; gq < 9; ++gq) {
        const float v = row[grp * 9 + gq];
        if (v <= T[8]) break;
        topk9_insert(T, v);
      }
    }
    float* dst = partials + (size_t)(R0 + t) * 9;       // slot 0
#pragma unroll
    for (int q = 0; q < 9; ++q) dst[q] = T[q];
    bound9d[R0 + t] = T[8];
  }
}

// ---------------- kernel 2b: mixed 128-tiles (2i,2i+1) -> slot 1 ----------------
__global__ __launch_bounds__(512) void k_mixed(
    const u16* __restrict__ F, float* __restrict__ partials,
    const float* __restrict__ bound9d)
{
  const int rb = 2 * blockIdx.x;
  const int cb = rb + 1;

  __shared__ char smem[65536];
  float* listR = (float*)smem;                    // [128][33]
  float* listC = (float*)(smem + 16896);
  float* bRs   = (float*)(smem + 33792);
  float* bCs   = (float*)(smem + 34304);
  int*   cntR  = (int*)(smem + 34816);
  int*   cntC  = (int*)(smem + 35328);
  uint2* ovfR  = (uint2*)(smem + 35840);
  uint2* ovfC  = (uint2*)(smem + 37888);
  int*   ovfn  = (int*)(smem + 39936);

  const int t    = threadIdx.x;
  const int lane = t & 63;
  const int w    = t >> 6;
  const int wr   = (w >> 2) * 64;
  const int wc   = (w & 3) * 32;
  const int R0   = rb * 128;
  const int C0   = cb * 128;

  f32x4 acc[4][2];
#pragma unroll
  for (int i = 0; i < 4; ++i)
#pragma unroll
    for (int j = 0; j < 2; ++j)
      acc[i][j] = {0.f, 0.f, 0.f, 0.f};

  gemm_tile8(acc, (const char*)(F + (size_t)R0 * DM),
             (const char*)(F + (size_t)C0 * DM), smem, t, lane, wr, wc);

  if (t < 128)      { bRs[t] = bound9d[R0 + t]; cntR[t] = 0; }
  else if (t < 256) { bCs[t - 128] = bound9d[C0 + t - 128]; cntC[t - 128] = 0; }
  if (t == 256) { ovfn[0] = 0; ovfn[1] = 0; }
  __syncthreads();

  float br[4][4];
#pragma unroll
  for (int i = 0; i < 4; ++i)
#pragma unroll
    for (int q = 0; q < 4; ++q)
      br[i][q] = bRs[wr + i * 16 + (lane >> 4) * 4 + q];
  float bcv[2];
#pragma unroll
  for (int j = 0; j < 2; ++j)
    bcv[j] = bCs[wc + j * 16 + (lane & 15)];

#pragma unroll
  for (int i = 0; i < 4; ++i)
#pragma unroll
    for (int j = 0; j < 2; ++j)
#pragma unroll
      for (int q = 0; q < 4; ++q) {
        const float v = acc[i][j][q];
        if (v > br[i][q]) {
          const int rr = wr + i * 16 + (lane >> 4) * 4 + q;
          const int s  = atomicAdd(&cntR[rr], 1);
          if (s < RCAP) listR[rr * 33 + s] = v;
          else { const int o = atomicAdd(&ovfn[0], 1);
                 if (o < OCAP) ovfR[o] = make_uint2((unsigned)rr, __float_as_uint(v)); }
        }
        if (v > bcv[j]) {
          const int cc = wc + j * 16 + (lane & 15);
          const int s  = atomicAdd(&cntC[cc], 1);
          if (s < RCAP) listC[cc * 33 + s] = v;
          else { const int o = atomicAdd(&ovfn[1], 1);
                 if (o < OCAP) ovfC[o] = make_uint2((unsigned)cc, __float_as_uint(v)); }
        }
      }
  __syncthreads();

  if (t < 128) {
    float T[9];
    const float b = bRs[t];
#pragma unroll
    for (int q = 0; q < 9; ++q) T[q] = b;
    const int n = min(cntR[t], RCAP);
    for (int e = 0; e < n; ++e) topk9_insert(T, listR[t * 33 + e]);
    const int no = min(ovfn[0], OCAP);
    for (int e = 0; e < no; ++e) {
      const uint2 u = ovfR[e];
      if ((int)u.x == t) topk9_insert(T, __uint_as_float(u.y));
    }
    float* dst = partials + ((size_t)1 * NROWS + R0 + t) * 9;   // slot 1
#pragma unroll
    for (int q = 0; q < 9; ++q) dst[q] = T[q];
  } else if (t < 256) {
    const int c = t - 128;
    float T[9];
    const float b = bCs[c];
#pragma unroll
    for (int q = 0; q < 9; ++q) T[q] = b;
    const int n = min(cntC[c], RCAP);
    for (int e = 0; e < n; ++e) topk9_insert(T, listC[c * 33 + e]);
    const int no = min(ovfn[1], OCAP);
    for (int e = 0; e < no; ++e) {
      const uint2 u = ovfC[e];
      if ((int)u.x == c) topk9_insert(T, __uint_as_float(u.y));
    }
    float* dst = partials + ((size_t)1 * NROWS + C0 + c) * 9;   // slot 1
#pragma unroll
    for (int q = 0; q < 9; ++q) dst[q] = T[q];
  }
}

// ---------------- kernel 2c: merge slot0+slot1 -> slot0, tight bound9 ----------------
__global__ __launch_bounds__(256) void k_bound(
    float* __restrict__ partials, float* __restrict__ bound9)
{
  const int n = blockIdx.x * 256 + threadIdx.x;
  if (n >= NROWS) return;
  float T[9];
  float* p0 = partials + (size_t)n * 9;
#pragma unroll
  for (int q = 0; q < 9; ++q) T[q] = p0[q];
  const float* p1 = partials + ((size_t)NROWS + n) * 9;
  for (int gq = 0; gq < 9; ++gq) {
    const float v = p1[gq];
    if (v <= T[8]) break;
    topk9_insert(T, v);
  }
#pragma unroll
  for (int q = 0; q < 9; ++q) p0[q] = T[q];
  bound9[n] = T[8];
}

// ---------------- kernel 2d: 256-tiles, counted-vmcnt ring + register gate ----------------
__global__ __launch_bounds__(512) void k_offdiag256(
    const u16* __restrict__ F, float* __restrict__ partials,
    const float* __restrict__ bound9)
{
  // decode idx -> (r2, c2), c2 > r2, over 32-triangle
  const int idx = blockIdx.x;
  int r2 = (int)(31.5 - sqrt(992.25 - 2.0 * (double)idx));
  while (31 * r2 - r2 * (r2 - 1) / 2 > idx) --r2;
  while (31 * (r2 + 1) - (r2 + 1) * r2 / 2 <= idx) ++r2;
  const int c2 = r2 + 1 + (idx - (31 * r2 - r2 * (r2 - 1) / 2));

  __shared__ char smem[131072];            // 4 ring buffers x 32 KB
  const int t    = threadIdx.x;
  const int lane = t & 63;
  const int w    = t >> 6;
  const int wm   = w >> 2;                 // 0..1
  const int wn   = w & 3;                  // 0..3
  const int R0   = r2 * 256;
  const int C0   = c2 * 256;

  f32x4 acc[8][4];
#pragma unroll
  for (int i = 0; i < 8; ++i)
#pragma unroll
    for (int j = 0; j < 4; ++j)
      acc[i][j] = {0.f, 0.f, 0.f, 0.f};

  const char* A = (const char*)(F + (size_t)R0 * DM);
  const char* B = (const char*)(F + (size_t)C0 * DM);

  // counted-vmcnt ring: 3-deep prefetch, never drain to 0 in the loop.
  // stage k uses 4 GLDS/thread; vmcnt(8) == own stage-k loads retired.
  stage256r(A, B, 0,   smem, 0, t);
  stage256r(A, B, 64,  smem, 1, t);
  stage256r(A, B, 128, smem, 2, t);
  for (int k = 0; k < 32; ++k) {
    if (k < 30)       asm volatile("s_waitcnt vmcnt(8)" ::: "memory");
    else if (k == 30) asm volatile("s_waitcnt vmcnt(4)" ::: "memory");
    else              asm volatile("s_waitcnt vmcnt(0)" ::: "memory");
    __builtin_amdgcn_s_barrier();          // stage(k) visible to all; compute(k-1) done
    if (k < 29)
      stage256r(A, B, (k + 3) * 64, smem, (k + 3) & 3, t);  // overwrites buf (k-1)&3
    compute256r(acc, (const u16*)(smem + (k & 3) * 32768), lane, wm, wn);
  }
  __syncthreads();                         // all LDS reads done before gate overlay

  // gate overlay
  float* bRs   = (float*)smem;                    // [256]
  float* bCs   = (float*)(smem + 1024);           // [256]
  int*   cntR  = (int*)(smem + 2048);
  int*   cntC  = (int*)(smem + 3072);
  uint2* ovfR  = (uint2*)(smem + 4096);           // [OCAP2]
  uint2* ovfC  = (uint2*)(smem + 8192);
  int*   ovfn  = (int*)(smem + 12288);
  float* listR = (float*)(smem + 16384);          // [256][25]
  float* listC = (float*)(smem + 16384 + 25600);  // [256][25]

  if (t < 256) { bRs[t] = bound9[R0 + t]; cntR[t] = 0; }
  else         { bCs[t - 256] = bound9[C0 + t - 256]; cntC[t - 256] = 0; }
  if (t == 0) { ovfn[0] = 0; ovfn[1] = 0; }
  __syncthreads();

  float bcv[4];
#pragma unroll
  for (int j = 0; j < 4; ++j)
    bcv[j] = bCs[wn * 64 + j * 16 + (lane & 15)];

#pragma unroll
  for (int i = 0; i < 8; ++i)
#pragma unroll
    for (int q = 0; q < 4; ++q) {
      const int rr = wm * 128 + i * 16 + (lane >> 4) * 4 + q;
      const float brv = bRs[rr];              // broadcast within 16-lane group
#pragma unroll
      for (int j = 0; j < 4; ++j) {
        const float v = acc[i][j][q];
        if (v > brv) {
          const int s = atomicAdd(&cntR[rr], 1);
          if (s < RCAP2) listR[rr * 25 + s] = v;
          else { const int o = atomicAdd(&ovfn[0], 1);
                 if (o < OCAP2) ovfR[o] = make_uint2((unsigned)rr, __float_as_uint(v)); }
        }
        if (v > bcv[j]) {
          const int cc = wn * 64 + j * 16 + (lane & 15);
          const int s = atomicAdd(&cntC[cc], 1);
          if (s < RCAP2) listC[cc * 25 + s] = v;
          else { const int o = atomicAdd(&ovfn[1], 1);
                 if (o < OCAP2) ovfC[o] = make_uint2((unsigned)cc, __float_as_uint(v)); }
        }
      }
    }
  __syncthreads();

  if (t < 256) {
    float T[9];
    const float b = bRs[t];
#pragma unroll
    for (int q = 0; q < 9; ++q) T[q] = b;
    const int n = min(cntR[t], RCAP2);
    for (int e = 0; e < n; ++e) topk9_insert(T, listR[t * 25 + e]);
    const int no = min(ovfn[0], OCAP2);
    for (int e = 0; e < no; ++e) {
      const uint2 u = ovfR[e];
      if ((int)u.x == t) topk9_insert(T, __uint_as_float(u.y));
    }
    const int slot = c2 + 1;                 // 2..32
    float* dst = partials + ((size_t)slot * NROWS + R0 + t) * 9;
#pragma unroll
    for (int q = 0; q < 9; ++q) dst[q] = T[q];
  } else {
    const int c = t - 256;
    float T[9];
    const float b = bCs[c];
#pragma unroll
    for (int q = 0; q < 9; ++q) T[q] = b;
    const int n = min(cntC[c], RCAP2);
    for (int e = 0; e < n; ++e) topk9_insert(T, listC[c * 25 + e]);
    const int no = min(ovfn[1], OCAP2);
    for (int e = 0; e < no; ++e) {
      const uint2 u = ovfC[e];
      if ((int)u.x == c) topk9_insert(T, __uint_as_float(u.y));
    }
    const int slot = 2 + r2;                 // 2..32
    float* dst = partials + ((size_t)slot * NROWS + C0 + c) * 9;
#pragma unroll
    for (int q = 0; q < 9; ++q) dst[q] = T[q];
  }
}

// ---------------- kernel 3: finalize, 4 threads/row over 33 slots ----------------
__global__ __launch_bounds__(256) void k_finalize(
    const float* __restrict__ partials, const float* __restrict__ CL,
    const float* __restrict__ W1, const float* __restrict__ b1,
    const float* __restrict__ W2, const float* __restrict__ b2,
    const float* __restrict__ alpha, float* __restrict__ out)
{
  const int t    = threadIdx.x;
  const int r    = t >> 2;
  const int part = t & 3;
  const int n    = blockIdx.x * 64 + r;

  __shared__ float Ms[64][37];

  float S[9];
  if (part == 0) {
    const float* p0 = partials + (size_t)n * 9;           // slot 0 (merged)
#pragma unroll
    for (int q = 0; q < 9; ++q) S[q] = p0[q];
  } else {
#pragma unroll
    for (int q = 0; q < 9; ++q) S[q] = -1e30f;
  }
  const int gs = 2 + part * 8;
  const int ge = (gs + 8 < NSLOT) ? gs + 8 : NSLOT;
  for (int g = gs; g < ge; ++g) {
    const float* p = partials + ((size_t)g * NROWS + n) * 9;
    for (int gq = 0; gq < 9; ++gq) {
      const float v = p[gq];
      if (v <= S[8]) break;
      topk9_insert(S, v);
    }
  }
#pragma unroll
  for (int q = 0; q < 9; ++q) Ms[r][part * 9 + q] = S[q];
  __syncthreads();
  if (part != 0) return;

  float T[9];
#pragma unroll
  for (int q = 0; q < 9; ++q) T[q] = Ms[r][q];
#pragma unroll
  for (int grp = 1; grp < 4; ++grp) {
    for (int gq = 0; gq < 9; ++gq) {
      const float v = Ms[r][grp * 9 + gq];
      if (v <= T[8]) break;
      topk9_insert(T, v);
    }
  }
  float sum = 0.f, sumsq = 0.f;
#pragma unroll
  for (int q = 1; q < 9; ++q) { sum += T[q]; sumsq += T[q] * T[q]; }
  const float mean_s  = sum * 0.125f;
  float var = (sumsq - 8.f * mean_s * mean_s) * (1.f / 7.f);
  var = fmaxf(var, 0.f);
  const float tree    = sqrtf(var);
  const float density = 1.f - mean_s;
  const float outlier = (1.f - T[8]) / (density + EPSF);

  float a0 = b2[0], a1 = b2[1], a2 = b2[2];
#pragma unroll
  for (int j = 0; j < 32; ++j) {
    float hj = W1[j*3+0]*tree + W1[j*3+1]*density + W1[j*3+2]*outlier + b1[j];
    hj = fmaxf(hj, 0.f);
    a0 += W2[j]      * hj;
    a1 += W2[32 + j] * hj;
    a2 += W2[64 + j] * hj;
  }
  const float mix = 1.f / (1.f + expf(-alpha[0]));
  const float im  = 1.f - mix;
  const float l0 = mix * CL[n*3+0] + im * a0;
  const float l1 = mix * CL[n*3+1] + im * a1;
  const float l2 = mix * CL[n*3+2] + im * a2;
  const float mx = fmaxf(l0, fmaxf(l1, l2));
  const float e0 = expf(l0 - mx), e1 = expf(l1 - mx), e2 = expf(l2 - mx);
  const float inv = 1.f / (e0 + e1 + e2);
  out[n*3+0] = e0 * inv;
  out[n*3+1] = e1 * inv;
  out[n*3+2] = e2 * inv;
  float* outl = out + NROWS * 3;
  outl[n*3+0] = l0;
  outl[n*3+1] = l1;
  outl[n*3+2] = l2;
}

extern "C" void kernel_launch(void* const* d_in, const int* in_sizes, int n_in,
                              void* d_out, int out_size, void* d_ws, size_t ws_size,
                              hipStream_t stream) {
  const float* H     = (const float*)d_in[0];
  const float* Wc    = (const float*)d_in[1];
  const float* bc    = (const float*)d_in[2];
  const float* W1    = (const float*)d_in[3];
  const float* b1    = (const float*)d_in[4];
  const float* W2    = (const float*)d_in[5];
  const float* b2    = (const float*)d_in[6];
  const float* alpha = (const float*)d_in[7];
  float* out = (float*)d_out;

  char* ws = (char*)d_ws;
  u16*   F        = (u16*)ws;                               // 16 MiB
  float* CL       = (float*)(ws + 16777216);                // 96 KiB
  float* partials = (float*)(ws + 16875520);                // 33*8192*9*4 = 9.73 MB
  float* bound9d  = (float*)(ws + 16875520 + 9732096);      // 32 KiB
  float* bound9   = (float*)(ws + 16875520 + 9732096 + 32768);

  k_rowprep<<<NROWS, 256, 0, stream>>>(H, Wc, bc, F, CL);
  k_diag<<<NRB, 512, 0, stream>>>(F, partials, bound9d);
  k_mixed<<<NMIX, 512, 0, stream>>>(F, partials, bound9d);
  k_bound<<<NROWS / 256, 256, 0, stream>>>(partials, bound9);
  k_offdiag256<<<NOFF2, 512, 0, stream>>>(F, partials, bound9);
  k_finalize<<<NROWS / 64, 256, 0, stream>>>(partials, CL, W1, b1, W2, b2, alpha, out);
}

// Round 22
// 148.312 us; speedup vs baseline: 1.1843x; 1.1843x over previous
//
#include <hip/hip_runtime.h>
#include <hip/hip_bf16.h>

typedef __attribute__((ext_vector_type(4))) float f32x4;
typedef __attribute__((ext_vector_type(8))) short short8;
typedef unsigned short u16;

#define NROWS 8192
#define DM 1024
#define EPSF 1e-8f
#define NRB 64        // 128-row blocks
#define NSLOT 64      // contributor lists per row
#define NOFFD 2016    // NRB*(NRB-1)/2 strict-upper tiles
#define RCAP 32       // per-row candidate capacity (lambda ~8)
#define OCAP 256      // overflow backstop capacity

// async global->LDS, 16B per lane, wave-uniform LDS base (rule #21: linear dest,
// inverse-swizzled SOURCE, swizzle applied again on the ds_read side)
#define GLDS(gsrc, ldst) __builtin_amdgcn_global_load_lds(                 \
    (const __attribute__((address_space(1))) void*)(gsrc),                 \
    (__attribute__((address_space(3))) void*)(ldst), 16, 0, 0)

static __device__ __forceinline__ u16 f2bf(float x) {
  unsigned u = __float_as_uint(x);
  u += 0x7fffu + ((u >> 16) & 1u);   // RNE
  return (u16)(u >> 16);
}

static __device__ __forceinline__ void topk9_insert(float (&S)[9], float v) {
  if (v <= S[8]) return;
  S[8] = v;
#pragma unroll
  for (int q = 8; q > 0; --q) {
    float a = S[q - 1], b = S[q];
    S[q - 1] = fmaxf(a, b);
    S[q]     = fminf(a, b);
  }
}

// vectorized scan of a 32-col strip of one spilled row (rotate-slot layout)
static __device__ __forceinline__ void scan_row_strip8(
    float (&S)[9], const float* __restrict__ crow, int row, int cbase) {
#pragma unroll
  for (int g = 0; g < 8; ++g) {
    const int c0   = cbase + 4 * g;
    const int slot = ((c0 >> 2) + row) & 31;           // additive rotate, 2-way free
    const f32x4 v  = *(const f32x4*)(crow + (slot << 2));
    const float m  = fmaxf(fmaxf(v.x, v.y), fmaxf(v.z, v.w));
    if (m > S[8]) {
      topk9_insert(S, v.x); topk9_insert(S, v.y);
      topk9_insert(S, v.z); topk9_insert(S, v.w);
    }
  }
}

// issue one K-step's async staging (512 threads: 2 A + 2 B chunks each)
static __device__ __forceinline__ void stage_tile8(
    const char* __restrict__ Abase, const char* __restrict__ Bbase,
    int k0b, char* smem, int aoff, int boff, int t)
{
  const int wbase = t & ~63;
#pragma unroll
  for (int it = 0; it < 2; ++it) {
    const int p  = it * 512 + t;
    const int so = (p >> 3) * (DM * 2) + (((p & 7) ^ ((p >> 3) & 7)) * 16);
    GLDS(Abase + k0b + so, smem + aoff + (it * 512 + wbase) * 16);
    GLDS(Bbase + k0b + so, smem + boff + (it * 512 + wbase) * 16);
  }
}

// A-only staging for diagonal tiles (B panel == A panel)
static __device__ __forceinline__ void stage_tileA(
    const char* __restrict__ Abase, int k0b, char* smem, int aoff, int t)
{
  const int wbase = t & ~63;
#pragma unroll
  for (int it = 0; it < 2; ++it) {
    const int p  = it * 512 + t;
    const int so = (p >> 3) * (DM * 2) + (((p & 7) ^ ((p >> 3) & 7)) * 16);
    GLDS(Abase + k0b + so, smem + aoff + (it * 512 + wbase) * 16);
  }
}

// one K-step of MFMA (wave tile 64x32 -> acc[4][2])
static __device__ __forceinline__ void compute_tile8(
    f32x4 (&acc)[4][2], const u16* __restrict__ As, const u16* __restrict__ Bs,
    int lane, int wr, int wc)
{
#pragma unroll
  for (int ks = 0; ks < 2; ++ks) {
    const int co = ((ks * 4 + (lane >> 4)) ^ (lane & 7)) * 8;
    short8 b[2];
#pragma unroll
    for (int j = 0; j < 2; ++j)
      b[j] = *(const short8*)(Bs + (wc + j * 16 + (lane & 15)) * 64 + co);
#pragma unroll
    for (int i = 0; i < 4; ++i) {
      const short8 a = *(const short8*)(As + (wr + i * 16 + (lane & 15)) * 64 + co);
#pragma unroll
      for (int j = 0; j < 2; ++j)
        acc[i][j] = __builtin_amdgcn_mfma_f32_16x16x32_bf16(a, b[j], acc[i][j], 0, 0, 0);
    }
  }
}

// full-K 2-phase double-buffered GEMM of one 128x128 tile (8 waves)
static __device__ __forceinline__ void gemm_tile8(
    f32x4 (&acc)[4][2], const char* Abase, const char* Bbase,
    char* smem, int t, int lane, int wr, int wc)
{
  u16* A0s = (u16*)smem;
  u16* B0s = (u16*)(smem + 16384);
  u16* A1s = (u16*)(smem + 32768);
  u16* B1s = (u16*)(smem + 49152);
  stage_tile8(Abase, Bbase, 0, smem, 0, 16384, t);
  __syncthreads();
  for (int kkp = 0; kkp < 8; ++kkp) {
    const int kb = kkp * 256;
    stage_tile8(Abase, Bbase, kb + 128, smem, 32768, 49152, t);
    compute_tile8(acc, A0s, B0s, lane, wr, wc);
    __syncthreads();
    if (kkp < 7)
      stage_tile8(Abase, Bbase, kb + 256, smem, 0, 16384, t);
    compute_tile8(acc, A1s, B1s, lane, wr, wc);
    __syncthreads();
  }
}

// diagonal variant: stage A only; both MFMA operands read from the A buffer
static __device__ __forceinline__ void gemm_tile8_diag(
    f32x4 (&acc)[4][2], const char* Abase,
    char* smem, int t, int lane, int wr, int wc)
{
  u16* A0s = (u16*)smem;
  u16* A1s = (u16*)(smem + 16384);
  stage_tileA(Abase, 0, smem, 0, t);
  __syncthreads();
  for (int kkp = 0; kkp < 8; ++kkp) {
    const int kb = kkp * 256;
    stage_tileA(Abase, kb + 128, smem, 16384, t);
    compute_tile8(acc, A0s, A0s, lane, wr, wc);
    __syncthreads();
    if (kkp < 7)
      stage_tileA(Abase, kb + 256, smem, 0, t);
    compute_tile8(acc, A1s, A1s, lane, wr, wc);
    __syncthreads();
  }
}

// normal spill (scalar, rotate-slot): wave region 64x32; writes <=2-way
static __device__ __forceinline__ void spill_normal8(
    float* Cs, const f32x4 (&acc)[4][2], int lane, int wr, int wc)
{
#pragma unroll
  for (int i = 0; i < 4; ++i)
#pragma unroll
    for (int j = 0; j < 2; ++j)
#pragma unroll
      for (int q = 0; q < 4; ++q) {
        const int rr = wr + i * 16 + (lane >> 4) * 4 + q;
        const int cc = wc + j * 16 + (lane & 15);
        const int slot = ((cc >> 2) + rr) & 31;
        Cs[rr * 128 + (slot << 2) + (cc & 3)] = acc[i][j][q];
      }
}

// ---------------- kernel 1: row norm -> bf16 F, content logits ----------------
__global__ __launch_bounds__(256) void k_rowprep(
    const float* __restrict__ H, const float* __restrict__ Wc,
    const float* __restrict__ bc, u16* __restrict__ F, float* __restrict__ CL)
{
  const int r = blockIdx.x;
  const int t = threadIdx.x;
  const int lane = t & 63;
  const int w = t >> 6;

  const float4 h  = ((const float4*)(H  + (size_t)r * DM))[t];
  const float4 c0 = ((const float4*)(Wc + 0 * DM))[t];
  const float4 c1 = ((const float4*)(Wc + 1 * DM))[t];
  const float4 c2 = ((const float4*)(Wc + 2 * DM))[t];

  float ss = h.x*h.x + h.y*h.y + h.z*h.z + h.w*h.w;
  float d0 = h.x*c0.x + h.y*c0.y + h.z*c0.z + h.w*c0.w;
  float d1 = h.x*c1.x + h.y*c1.y + h.z*c1.z + h.w*c1.w;
  float d2 = h.x*c2.x + h.y*c2.y + h.z*c2.z + h.w*c2.w;

#pragma unroll
  for (int off = 32; off > 0; off >>= 1) {
    ss += __shfl_down(ss, off);
    d0 += __shfl_down(d0, off);
    d1 += __shfl_down(d1, off);
    d2 += __shfl_down(d2, off);
  }
  __shared__ float red[4][4];
  __shared__ float bcast;
  if (lane == 0) { red[w][0] = ss; red[w][1] = d0; red[w][2] = d1; red[w][3] = d2; }
  __syncthreads();
  if (t == 0) {
    float S  = red[0][0] + red[1][0] + red[2][0] + red[3][0];
    float D0 = red[0][1] + red[1][1] + red[2][1] + red[3][1];
    float D1 = red[0][2] + red[1][2] + red[2][2] + red[3][2];
    float D2 = red[0][3] + red[1][3] + red[2][3] + red[3][3];
    bcast = 1.0f / (sqrtf(S) + EPSF);
    CL[r*3+0] = D0 + bc[0];
    CL[r*3+1] = D1 + bc[1];
    CL[r*3+2] = D2 + bc[2];
  }
  __syncthreads();
  const float invn = bcast;
  ushort4 o;
  o.x = f2bf(h.x * invn); o.y = f2bf(h.y * invn);
  o.z = f2bf(h.z * invn); o.w = f2bf(h.w * invn);
  ((ushort4*)(F + (size_t)r * DM))[t] = o;
}

// ---------------- kernel 2a: diagonal tiles -> partials + per-row bound ----------------
// full 128x128 tile, 512 threads, A-only staging (B panel == A panel)
__global__ __launch_bounds__(512) void k_diag(
    const u16* __restrict__ F, float* __restrict__ partials, float* __restrict__ bound9)
{
  const int rb = blockIdx.x;
  __shared__ char smem[65536];
  float* Cs = (float*)smem;
  float* Ms = (float*)smem;

  const int t    = threadIdx.x;
  const int lane = t & 63;
  const int w    = t >> 6;
  const int wr   = (w >> 2) * 64;
  const int wc   = (w & 3) * 32;
  const int R0   = rb * 128;

  f32x4 acc[4][2];
#pragma unroll
  for (int i = 0; i < 4; ++i)
#pragma unroll
    for (int j = 0; j < 2; ++j)
      acc[i][j] = {0.f, 0.f, 0.f, 0.f};

  gemm_tile8_diag(acc, (const char*)(F + (size_t)R0 * DM), smem, t, lane, wr, wc);

  spill_normal8(Cs, acc, lane, wr, wc);
  __syncthreads();

  float sR[9];
#pragma unroll
  for (int q = 0; q < 9; ++q) sR[q] = -1e30f;
  scan_row_strip8(sR, Cs + (t >> 2) * 128, t >> 2, (t & 3) * 32);
  __syncthreads();

#pragma unroll
  for (int q = 0; q < 9; ++q) Ms[(t >> 2) * 36 + (t & 3) * 9 + q] = sR[q];
  __syncthreads();
  if (t < 128) {
    const float* row = Ms + t * 36;
    float T[9];
#pragma unroll
    for (int q = 0; q < 9; ++q) T[q] = row[q];
#pragma unroll
    for (int grp = 1; grp < 4; ++grp) {
      for (int gq = 0; gq < 9; ++gq) {
        const float v = row[grp * 9 + gq];
        if (v <= T[8]) break;
        topk9_insert(T, v);
      }
    }
    float* dst = partials + ((size_t)rb * NROWS + R0 + t) * 9;
#pragma unroll
    for (int q = 0; q < 9; ++q) dst[q] = T[q];
    bound9[R0 + t] = T[8];                 // valid lower bound for global 9th
  }
}

// ---------------- kernel 2b: off-diag tiles, per-row in-register gate ----------------
// No spill/scan. Each thread gates its 32 acc values against per-row/per-col
// bounds; passers (~6%, lambda~8/row) append to PER-ROW LDS lists (128+128
// counters spread atomic contention). Cleanup: thread t walks only its own
// row's <=32 entries + an (expected-empty) overflow backstop. Multiset-exact.
__global__ __launch_bounds__(512) void k_offdiag(
    const u16* __restrict__ F, float* __restrict__ partials,
    const float* __restrict__ bound9)
{
  // decode linear id -> (rb, cb), cb > rb ; offset(rb) = 63*rb - rb*(rb-1)/2
  const int idx = blockIdx.x;
  int rb = (int)(63.5 - sqrt(4032.25 - 2.0 * (double)idx));
  while (63 * rb - rb * (rb - 1) / 2 > idx) --rb;
  while (63 * (rb + 1) - (rb + 1) * rb / 2 <= idx) ++rb;
  const int cb = rb + 1 + (idx - (63 * rb - rb * (rb - 1) / 2));

  __shared__ char smem[65536];
  float* listR = (float*)smem;                    // [128][33]
  float* listC = (float*)(smem + 16896);          // [128][33]
  float* bRs   = (float*)(smem + 33792);
  float* bCs   = (float*)(smem + 34304);
  int*   cntR  = (int*)(smem + 34816);
  int*   cntC  = (int*)(smem + 35328);
  uint2* ovfR  = (uint2*)(smem + 35840);
  uint2* ovfC  = (uint2*)(smem + 37888);
  int*   ovfn  = (int*)(smem + 39936);

  const int t    = threadIdx.x;
  const int lane = t & 63;
  const int w    = t >> 6;
  const int wr   = (w >> 2) * 64;
  const int wc   = (w & 3) * 32;
  const int R0   = rb * 128;
  const int C0   = cb * 128;

  f32x4 acc[4][2];
#pragma unroll
  for (int i = 0; i < 4; ++i)
#pragma unroll
    for (int j = 0; j < 2; ++j)
      acc[i][j] = {0.f, 0.f, 0.f, 0.f};

  gemm_tile8(acc, (const char*)(F + (size_t)R0 * DM),
             (const char*)(F + (size_t)C0 * DM), smem, t, lane, wr, wc);

  if (t < 128)      { bRs[t] = bound9[R0 + t]; cntR[t] = 0; }
  else if (t < 256) { bCs[t - 128] = bound9[C0 + t - 128]; cntC[t - 128] = 0; }
  if (t == 256) { ovfn[0] = 0; ovfn[1] = 0; }
  __syncthreads();

  float br[4][4];
#pragma unroll
  for (int i = 0; i < 4; ++i)
#pragma unroll
    for (int q = 0; q < 4; ++q)
      br[i][q] = bRs[wr + i * 16 + (lane >> 4) * 4 + q];
  float bcv[2];
#pragma unroll
  for (int j = 0; j < 2; ++j)
    bcv[j] = bCs[wc + j * 16 + (lane & 15)];

#pragma unroll
  for (int i = 0; i < 4; ++i)
#pragma unroll
    for (int j = 0; j < 2; ++j)
#pragma unroll
      for (int q = 0; q < 4; ++q) {
        const float v = acc[i][j][q];
        if (v > br[i][q]) {
          const int rr = wr + i * 16 + (lane >> 4) * 4 + q;
          const int s  = atomicAdd(&cntR[rr], 1);
          if (s < RCAP) listR[rr * 33 + s] = v;
          else { const int o = atomicAdd(&ovfn[0], 1);
                 if (o < OCAP) ovfR[o] = make_uint2((unsigned)rr, __float_as_uint(v)); }
        }
        if (v > bcv[j]) {
          const int cc = wc + j * 16 + (lane & 15);
          const int s  = atomicAdd(&cntC[cc], 1);
          if (s < RCAP) listC[cc * 33 + s] = v;
          else { const int o = atomicAdd(&ovfn[1], 1);
                 if (o < OCAP) ovfC[o] = make_uint2((unsigned)cc, __float_as_uint(v)); }
        }
      }
  __syncthreads();

  if (t < 128) {
    float T[9];
    const float b = bRs[t];
#pragma unroll
    for (int q = 0; q < 9; ++q) T[q] = b;
    const int n = min(cntR[t], RCAP);
    for (int e = 0; e < n; ++e) topk9_insert(T, listR[t * 33 + e]);
    const int no = min(ovfn[0], OCAP);
    for (int e = 0; e < no; ++e) {
      const uint2 u = ovfR[e];
      if ((int)u.x == t) topk9_insert(T, __uint_as_float(u.y));
    }
    float* dst = partials + ((size_t)cb * NROWS + R0 + t) * 9;
#pragma unroll
    for (int q = 0; q < 9; ++q) dst[q] = T[q];
  } else if (t < 256) {
    const int c = t - 128;
    float T[9];
    const float b = bCs[c];
#pragma unroll
    for (int q = 0; q < 9; ++q) T[q] = b;
    const int n = min(cntC[c], RCAP);
    for (int e = 0; e < n; ++e) topk9_insert(T, listC[c * 33 + e]);
    const int no = min(ovfn[1], OCAP);
    for (int e = 0; e < no; ++e) {
      const uint2 u = ovfC[e];
      if ((int)u.x == c) topk9_insert(T, __uint_as_float(u.y));
    }
    float* dst = partials + ((size_t)rb * NROWS + C0 + c) * 9;
#pragma unroll
    for (int q = 0; q < 9; ++q) dst[q] = T[q];
  }
}

// ---------------- kernel 3: finalize, 4 threads per row (latency-parallel) ----------------
// Each row's 64-group merge split across 4 threads (16 groups each, early-break);
// the 4 partial top-9s merge in LDS. Union of partial top-9s contains the global
// top-9 -> exact. Chain of dependent group-loads shortened 64 -> 16.
__global__ __launch_bounds__(256) void k_finalize(
    const float* __restrict__ partials, const float* __restrict__ CL,
    const float* __restrict__ W1, const float* __restrict__ b1,
    const float* __restrict__ W2, const float* __restrict__ b2,
    const float* __restrict__ alpha, float* __restrict__ out)
{
  const int t    = threadIdx.x;
  const int r    = t >> 2;                 // 0..63 row within block
  const int part = t & 3;
  const int n    = blockIdx.x * 64 + r;

  __shared__ float Ms[64][37];

  float S[9];
#pragma unroll
  for (int q = 0; q < 9; ++q) S[q] = -1e30f;
  const int g0 = part * 16;
  for (int g = g0; g < g0 + 16; ++g) {
    const float* p = partials + ((size_t)g * NROWS + n) * 9;
    for (int gq = 0; gq < 9; ++gq) {
      const float v = p[gq];
      if (v <= S[8]) break;               // group lists are descending
      topk9_insert(S, v);
    }
  }
#pragma unroll
  for (int q = 0; q < 9; ++q) Ms[r][part * 9 + q] = S[q];
  __syncthreads();
  if (part != 0) return;

  float T[9];
#pragma unroll
  for (int q = 0; q < 9; ++q) T[q] = Ms[r][q];
#pragma unroll
  for (int grp = 1; grp < 4; ++grp) {
    for (int gq = 0; gq < 9; ++gq) {
      const float v = Ms[r][grp * 9 + gq];
      if (v <= T[8]) break;
      topk9_insert(T, v);
    }
  }
  // T[0] is the self-similarity (max, appears exactly once) -> dropped
  float sum = 0.f, sumsq = 0.f;
#pragma unroll
  for (int q = 1; q < 9; ++q) { sum += T[q]; sumsq += T[q] * T[q]; }
  const float mean_s  = sum * 0.125f;
  float var = (sumsq - 8.f * mean_s * mean_s) * (1.f / 7.f);  // ddof=1
  var = fmaxf(var, 0.f);
  const float tree    = sqrtf(var);
  const float density = 1.f - mean_s;
  const float outlier = (1.f - T[8]) / (density + EPSF);      // min sim = max dist

  float a0 = b2[0], a1 = b2[1], a2 = b2[2];
#pragma unroll
  for (int j = 0; j < 32; ++j) {
    float hj = W1[j*3+0]*tree + W1[j*3+1]*density + W1[j*3+2]*outlier + b1[j];
    hj = fmaxf(hj, 0.f);
    a0 += W2[j]      * hj;
    a1 += W2[32 + j] * hj;
    a2 += W2[64 + j] * hj;
  }
  const float mix = 1.f / (1.f + expf(-alpha[0]));
  const float im  = 1.f - mix;
  const float l0 = mix * CL[n*3+0] + im * a0;
  const float l1 = mix * CL[n*3+1] + im * a1;
  const float l2 = mix * CL[n*3+2] + im * a2;
  const float mx = fmaxf(l0, fmaxf(l1, l2));
  const float e0 = expf(l0 - mx), e1 = expf(l1 - mx), e2 = expf(l2 - mx);
  const float inv = 1.f / (e0 + e1 + e2);
  out[n*3+0] = e0 * inv;
  out[n*3+1] = e1 * inv;
  out[n*3+2] = e2 * inv;
  float* outl = out + NROWS * 3;
  outl[n*3+0] = l0;
  outl[n*3+1] = l1;
  outl[n*3+2] = l2;
}

extern "C" void kernel_launch(void* const* d_in, const int* in_sizes, int n_in,
                              void* d_out, int out_size, void* d_ws, size_t ws_size,
                              hipStream_t stream) {
  const float* H     = (const float*)d_in[0];
  const float* Wc    = (const float*)d_in[1];
  const float* bc    = (const float*)d_in[2];
  const float* W1    = (const float*)d_in[3];
  const float* b1    = (const float*)d_in[4];
  const float* W2    = (const float*)d_in[5];
  const float* b2    = (const float*)d_in[6];
  const float* alpha = (const float*)d_in[7];
  float* out = (float*)d_out;

  char* ws = (char*)d_ws;
  u16*   F        = (u16*)ws;                               // 16 MiB
  float* CL       = (float*)(ws + 16777216);                // 96 KiB
  float* partials = (float*)(ws + 16777216 + 98304);        // 64*8192*9*4 = 18 MiB
  float* bound9   = (float*)(ws + 16777216 + 98304 + 18874368);  // 32 KiB

  k_rowprep<<<NROWS, 256, 0, stream>>>(H, Wc, bc, F, CL);
  k_diag<<<NRB, 512, 0, stream>>>(F, partials, bound9);
  k_offdiag<<<NOFFD, 512, 0, stream>>>(F, partials, bound9);
  k_finalize<<<NROWS / 64, 256, 0, stream>>>(partials, CL, W1, b1, W2, b2, alpha, out);
}